// Round 4
// baseline (180.248 us; speedup 1.0000x reference)
//
#include <hip/hip_runtime.h>

#define NSEG 21      // labels 0..20
#define NLBL 20
#define DIM  32
#define NREP 16      // LDS histogram replicas
#define VREP 16      // global replicas for vsum flush
#define DV   0.5f
#define DD   3.0f
#define BATCH 8
#define SEGF 693     // per-batch canonical: [21 counts][672 sums, d-major: 21 + d*21 + s]

// k_sums: pure linear sweep. Block owns 8192 consecutive floats of ONE (b,d) row.
// 8 float4 + 8 int4 loads batched into registers BEFORE any LDS op (MLP ~16KB/wave).
__global__ __launch_bounds__(256)
void k_sums(const float* __restrict__ emb, const int* __restrict__ seg,
            float* __restrict__ canon, int N) {
  __shared__ float s_bin[NREP * NSEG];
  __shared__ float s_cbin[NREP * NSEG];
  const int tid = threadIdx.x;
  const int f0 = blockIdx.x * 8192;          // flat float index into emb
  const int b  = f0 >> 21;                   // D*N = 1<<21
  const int d  = (f0 >> 16) & 31;            // N = 1<<16
  const int nb = f0 & 65535;
  for (int i = tid; i < NREP * NSEG; i += 256) { s_bin[i] = 0.f; s_cbin[i] = 0.f; }
  __syncthreads();

  const float4* e4 = reinterpret_cast<const float4*>(emb) + (f0 >> 2) + tid;
  const int4*   g4 = reinterpret_cast<const int4*>(seg) + b * (N >> 2) + (nb >> 2) + tid;
  float4 e[8]; int4 sg[8];
  #pragma unroll
  for (int g = 0; g < 8; ++g) e[g] = e4[g * 256];
  #pragma unroll
  for (int g = 0; g < 8; ++g) sg[g] = g4[g * 256];
  __builtin_amdgcn_sched_barrier(0);         // keep all 16 loads issued before LDS ops

  const int rb = (tid & (NREP - 1)) * NSEG;
  if (d == 0) {
    #pragma unroll
    for (int g = 0; g < 8; ++g) {
      atomicAdd(&s_bin[rb + sg[g].x], e[g].x);  atomicAdd(&s_cbin[rb + sg[g].x], 1.f);
      atomicAdd(&s_bin[rb + sg[g].y], e[g].y);  atomicAdd(&s_cbin[rb + sg[g].y], 1.f);
      atomicAdd(&s_bin[rb + sg[g].z], e[g].z);  atomicAdd(&s_cbin[rb + sg[g].z], 1.f);
      atomicAdd(&s_bin[rb + sg[g].w], e[g].w);  atomicAdd(&s_cbin[rb + sg[g].w], 1.f);
    }
  } else {
    #pragma unroll
    for (int g = 0; g < 8; ++g) {
      atomicAdd(&s_bin[rb + sg[g].x], e[g].x);
      atomicAdd(&s_bin[rb + sg[g].y], e[g].y);
      atomicAdd(&s_bin[rb + sg[g].z], e[g].z);
      atomicAdd(&s_bin[rb + sg[g].w], e[g].w);
    }
  }
  __syncthreads();
  if (tid < NSEG) {
    float v = 0.f;
    #pragma unroll
    for (int r = 0; r < NREP; ++r) v += s_bin[r * NSEG + tid];
    atomicAdd(&canon[b * SEGF + NSEG + d * NSEG + tid], v);
    if (d == 0) {
      float c = 0.f;
      #pragma unroll
      for (int r = 0; r < NREP; ++r) c += s_cbin[r * NSEG + tid];
      atomicAdd(&canon[b * SEGF + tid], c);
    }
  }
}

__global__ __launch_bounds__(256)
void k_var(const float* __restrict__ emb, const int* __restrict__ seg,
           const float* __restrict__ canon, float* __restrict__ vrep, int N) {
  __shared__ float s_m[NSEG * 33];
  __shared__ float s_c[NSEG];
  __shared__ float s_v[NREP * NSEG];
  const int tid = threadIdx.x;
  const int bx = blockIdx.x, b = blockIdx.y;
  const float* cb = canon + b * SEGF;
  if (tid < NSEG) s_c[tid] = fmaxf(cb[tid], 1.f);
  for (int i = tid; i < NREP * NSEG; i += 256) s_v[i] = 0.f;
  __syncthreads();
  for (int i = tid; i < DIM * NSEG; i += 256) {
    const int d = i / NSEG, s = i - d * NSEG;
    s_m[s * 33 + d] = cb[NSEG + i] / s_c[s];
  }
  __syncthreads();

  const int n = bx * 256 + tid;
  const int sl = seg[(size_t)b * N + n];
  const size_t base = (size_t)b * DIM * N + n;
  const int ml = sl * 33;
  float q = 0.f;
  #pragma unroll
  for (int d = 0; d < DIM; ++d) {
    const float e = emb[base + (size_t)d * N];
    const float t = e - s_m[ml + d];
    q += t * t;
  }
  if (sl > 0) {
    const float r = sqrtf(q) - DV;
    if (r > 0.f) atomicAdd(&s_v[(tid & (NREP - 1)) * NSEG + sl], r * r);
  }
  __syncthreads();
  if (tid < NSEG) {
    float v = 0.f;
    #pragma unroll
    for (int r = 0; r < NREP; ++r) v += s_v[r * NSEG + tid];
    atomicAdd(&vrep[((bx & (VREP - 1)) * BATCH + b) * NSEG + tid], v);
  }
}

__global__ __launch_bounds__(256)
void k_final(const float* __restrict__ canon, const float* __restrict__ vrep,
             float* __restrict__ out) {
  __shared__ float s_m[NLBL * 33];
  __shared__ float s_cnt[NSEG];
  __shared__ float s_vs[NSEG];
  __shared__ int   s_p[NLBL];
  __shared__ float s_dl;
  const int b = blockIdx.x;
  const int tid = threadIdx.x;
  const float* cb = canon + b * SEGF;
  if (tid < NSEG) {
    s_cnt[tid] = cb[tid];
    float v = 0.f;
    for (int r = 0; r < VREP; ++r) v += vrep[(r * BATCH + b) * NSEG + tid];
    s_vs[tid] = v;
  }
  if (tid == 0) s_dl = 0.f;
  __syncthreads();
  for (int i = tid; i < NLBL * DIM; i += 256) {
    const int l = i >> 5, d = i & 31;           // l -> label l+1
    s_m[l * 33 + d] = cb[NSEG + d * NSEG + (l + 1)] / fmaxf(s_cnt[l + 1], 1.f);
  }
  if (tid < NLBL) s_p[tid] = (s_cnt[tid + 1] > 0.f) ? 1 : 0;
  __syncthreads();
  float dl = 0.f;
  for (int p = tid; p < NLBL * NLBL; p += 256) {
    const int i = p / NLBL, j = p - (p / NLBL) * NLBL;
    if (i != j && s_p[i] && s_p[j]) {
      float sq = 0.f;
      #pragma unroll
      for (int d = 0; d < DIM; ++d) {
        const float t = s_m[i * 33 + d] - s_m[j * 33 + d];
        sq += t * t;
      }
      const float r = DD - sqrtf(sq);
      if (r > 0.f) dl += r * r;
    }
  }
  atomicAdd(&s_dl, dl);
  __syncthreads();
  if (tid == 0) {
    float nl = 0.f, var = 0.f;
    for (int l = 1; l <= NLBL; ++l)
      if (s_cnt[l] > 0.f) { nl += 1.f; var += s_vs[l] / s_cnt[l]; }
    const float vb = (nl > 0.f) ? var / nl : 0.f;
    const float db = (nl > 1.f) ? s_dl / fmaxf(nl * (nl - 1.f), 1.f) * 0.5f : 0.f;
    atomicAdd(&out[0], vb / (float)BATCH);
    atomicAdd(&out[1], db / (float)BATCH);
    // out[2] stays 0 from the memset
  }
}

extern "C" void kernel_launch(void* const* d_in, const int* in_sizes, int n_in,
                              void* d_out, int out_size, void* d_ws, size_t ws_size,
                              hipStream_t stream) {
  const float* emb = (const float*)d_in[0];
  const int*   seg = (const int*)d_in[1];
  float* out = (float*)d_out;
  float* ws  = (float*)d_ws;
  const int N = in_sizes[1] / BATCH;   // 65536

  float* canon = ws;                              // BATCH*SEGF
  float* vrep  = canon + BATCH * SEGF;            // VREP*BATCH*NSEG

  hipMemsetAsync(canon, 0,
                 (size_t)(BATCH * SEGF + VREP * BATCH * NSEG) * sizeof(float), stream);
  hipMemsetAsync(d_out, 0, (size_t)out_size * sizeof(float), stream);

  const int total_f = BATCH * DIM * N;            // 16M floats
  k_sums <<<dim3(total_f / 8192), 256, 0, stream>>>(emb, seg, canon, N);
  k_var  <<<dim3(N / 256, BATCH), 256, 0, stream>>>(emb, seg, canon, vrep, N);
  k_final<<<dim3(BATCH), 256, 0, stream>>>(canon, vrep, out);
}

// Round 5
// 147.464 us; speedup vs baseline: 1.2223x; 1.2223x over previous
//
#include <hip/hip_runtime.h>

#define NSEG 21
#define NLBL 20
#define DIM  32
#define NREP 16
#define VREP 16
#define PADC 9
#define DV   0.5f
#define DD   3.0f
#define BATCH 8
#define SEGF 693     // [21 counts][672 sums d-major: 21 + d*21 + s]
#define BINW 264     // per-thread column layout: bank (8s+lane)%32, conflict-free

// ---------------- probes (write only to ws; diagnostic) ----------------

// p_load: R3 k_sums load pattern EXACTLY, no LDS ops. Register sum -> 1 store/wave.
__global__ __launch_bounds__(256)
void p_load(const float* __restrict__ emb, const int* __restrict__ seg,
            float* __restrict__ probe, int N) {
  const int tid = threadIdx.x;
  const int bx = blockIdx.x, b = blockIdx.y, dz = blockIdx.z;
  const int n0 = bx * 1024 + tid * 4;
  const size_t base = (size_t)b * DIM * N + (size_t)dz * 8 * N + n0;
  const int4 s4 = *(const int4*)(seg + (size_t)b * N + n0);
  float acc = (float)(s4.x + s4.y + s4.z + s4.w);
  #pragma unroll
  for (int dd = 0; dd < 8; ++dd) {
    const float4 e = *(const float4*)(emb + base + (size_t)dd * N);
    acc += e.x + e.y + e.z + e.w;
  }
  #pragma unroll
  for (int off = 32; off; off >>= 1) acc += __shfl_down(acc, off, 64);
  if ((tid & 63) == 0) {
    const int fw = (((dz * gridDim.y + b) * gridDim.x + bx) << 2) + (tid >> 6);
    probe[fw & 8191] = acc;
  }
}

// p_ds: R3 k_sums LDS-atomic pattern EXACTLY (32 ds atomicAdds/thread into
// NREP-replicated bins), synthetic labels/values, no global loads.
__global__ __launch_bounds__(256)
void p_ds(float* __restrict__ probe) {
  __shared__ float s_sum[NREP * NSEG * PADC];
  __shared__ float s_cnt[NREP * NSEG];
  const int tid = threadIdx.x;
  const int bx = blockIdx.x, b = blockIdx.y, dz = blockIdx.z;
  for (int i = tid; i < NREP * NSEG * PADC; i += 256) s_sum[i] = 0.f;
  for (int i = tid; i < NREP * NSEG; i += 256) s_cnt[i] = 0.f;
  __syncthreads();
  const int rep = tid & (NREP - 1);
  unsigned h = tid * 2654435761u ^ bx * 3266489917u ^ b * 374761393u ^ dz * 668265263u;
  int a[4];
  #pragma unroll
  for (int p = 0; p < 4; ++p) {
    unsigned hp = h + (unsigned)p * 2246822519u;
    hp ^= hp >> 15; hp *= 2654435761u;
    a[p] = (int)(((hp >> 16) * NSEG) >> 16);       // 0..20
  }
  if (dz == 0) {
    #pragma unroll
    for (int p = 0; p < 4; ++p) atomicAdd(&s_cnt[rep * NSEG + a[p]], 1.f);
  }
  #pragma unroll
  for (int dd = 0; dd < 8; ++dd) {
    #pragma unroll
    for (int p = 0; p < 4; ++p) {
      const float v = (float)((h >> (p + dd)) & 255) * 0.00390625f;
      atomicAdd(&s_sum[(rep * NSEG + a[p]) * PADC + dd], v);
    }
  }
  __syncthreads();
  const int flat = (dz * gridDim.y + b) * gridDim.x + bx;
  if (tid < NSEG * PADC) {
    float v = 0.f;
    #pragma unroll
    for (int r = 0; r < NREP; ++r) v += s_sum[r * NSEG * PADC + tid];
    probe[8192 + (flat & 127) * 192 + tid] = v;
  }
}

// ---------------- real pipeline ----------------

// k_cnt: label histogram (counts) only; per-thread private LDS columns, no atomics.
__global__ __launch_bounds__(256)
void k_cnt(const int* __restrict__ seg, float* __restrict__ canon, int N) {
  __shared__ float bins[NSEG * BINW];
  const int tid = threadIdx.x;
  const int sp = blockIdx.x, b = blockIdx.y;
  for (int i = tid; i < NSEG * BINW; i += 256) bins[i] = 0.f;
  __syncthreads();
  const int4* g4 = (const int4*)(seg + (size_t)b * N + sp * 4096) + tid;
  #pragma unroll
  for (int u = 0; u < 4; ++u) {
    const int4 s = g4[u * 256];
    bins[s.x * BINW + tid] += 1.f;
    bins[s.y * BINW + tid] += 1.f;
    bins[s.z * BINW + tid] += 1.f;
    bins[s.w * BINW + tid] += 1.f;
  }
  __syncthreads();
  float p = 0.f;
  if (tid < NSEG * 8) {
    const int s = tid >> 3, j = tid & 7;
    #pragma unroll
    for (int k = 0; k < 33; ++k) p += bins[s * BINW + j * 33 + k];
  }
  __syncthreads();
  if (tid < NSEG * 8) bins[(tid >> 3) * BINW + (tid & 7)] = p;
  __syncthreads();
  if (tid < NSEG) {
    float v = 0.f;
    #pragma unroll
    for (int j = 0; j < 8; ++j) v += bins[tid * BINW + j];
    atomicAdd(&canon[b * SEGF + tid], v);
  }
}

// k_sums2: segment sums with ZERO LDS atomics. Thread owns column tid of each
// label row; plain ds_read+add+ds_write RMW (conflict-free banks).
__global__ __launch_bounds__(256)
void k_sums2(const float* __restrict__ emb, const int* __restrict__ seg,
             float* __restrict__ canon, int N) {
  __shared__ float bins[NSEG * BINW];
  const int tid = threadIdx.x;
  const int sp = blockIdx.x, d = blockIdx.y, b = blockIdx.z;
  for (int i = tid; i < NSEG * BINW; i += 256) bins[i] = 0.f;
  __syncthreads();
  const int n0 = sp * 16384;
  const float4* e4 = (const float4*)(emb + ((size_t)b * DIM + d) * N + n0) + tid;
  const int4*   g4 = (const int4*)(seg + (size_t)b * N + n0) + tid;
  #pragma unroll
  for (int c = 0; c < 4; ++c) {
    float4 e[4]; int4 s[4];
    #pragma unroll
    for (int u = 0; u < 4; ++u) { e[u] = e4[(c * 4 + u) * 256]; s[u] = g4[(c * 4 + u) * 256]; }
    #pragma unroll
    for (int u = 0; u < 4; ++u) {
      bins[s[u].x * BINW + tid] += e[u].x;
      bins[s[u].y * BINW + tid] += e[u].y;
      bins[s[u].z * BINW + tid] += e[u].z;
      bins[s[u].w * BINW + tid] += e[u].w;
    }
  }
  __syncthreads();
  float p = 0.f;
  if (tid < NSEG * 8) {
    const int s = tid >> 3, j = tid & 7;
    #pragma unroll
    for (int k = 0; k < 33; ++k) p += bins[s * BINW + j * 33 + k];
  }
  __syncthreads();
  if (tid < NSEG * 8) bins[(tid >> 3) * BINW + (tid & 7)] = p;
  __syncthreads();
  if (tid < NSEG) {
    float v = 0.f;
    #pragma unroll
    for (int j = 0; j < 8; ++j) v += bins[tid * BINW + j];
    atomicAdd(&canon[b * SEGF + NSEG + d * NSEG + tid], v);
  }
}

__global__ __launch_bounds__(256)
void k_var(const float* __restrict__ emb, const int* __restrict__ seg,
           const float* __restrict__ canon, float* __restrict__ vrep, int N) {
  __shared__ float s_m[NSEG * 33];
  __shared__ float s_c[NSEG];
  __shared__ float s_v[NREP * NSEG];
  const int tid = threadIdx.x;
  const int bx = blockIdx.x, b = blockIdx.y;
  const float* cb = canon + b * SEGF;
  if (tid < NSEG) s_c[tid] = fmaxf(cb[tid], 1.f);
  for (int i = tid; i < NREP * NSEG; i += 256) s_v[i] = 0.f;
  __syncthreads();
  for (int i = tid; i < DIM * NSEG; i += 256) {
    const int d = i / NSEG, s = i - d * NSEG;
    s_m[s * 33 + d] = cb[NSEG + i] / s_c[s];
  }
  __syncthreads();
  const int n = bx * 256 + tid;
  const int sl = seg[(size_t)b * N + n];
  const size_t base = (size_t)b * DIM * N + n;
  const int ml = sl * 33;
  float q = 0.f;
  #pragma unroll
  for (int d = 0; d < DIM; ++d) {
    const float e = emb[base + (size_t)d * N];
    const float t = e - s_m[ml + d];
    q += t * t;
  }
  if (sl > 0) {
    const float r = sqrtf(q) - DV;
    if (r > 0.f) atomicAdd(&s_v[(tid & (NREP - 1)) * NSEG + sl], r * r);
  }
  __syncthreads();
  if (tid < NSEG) {
    float v = 0.f;
    #pragma unroll
    for (int r = 0; r < NREP; ++r) v += s_v[r * NSEG + tid];
    atomicAdd(&vrep[((bx & (VREP - 1)) * BATCH + b) * NSEG + tid], v);
  }
}

__global__ __launch_bounds__(256)
void k_final(const float* __restrict__ canon, const float* __restrict__ vrep,
             float* __restrict__ out) {
  __shared__ float s_m[NLBL * 33];
  __shared__ float s_cnt[NSEG];
  __shared__ float s_vs[NSEG];
  __shared__ int   s_p[NLBL];
  __shared__ float s_dl;
  const int b = blockIdx.x;
  const int tid = threadIdx.x;
  const float* cb = canon + b * SEGF;
  if (tid < NSEG) {
    s_cnt[tid] = cb[tid];
    float v = 0.f;
    for (int r = 0; r < VREP; ++r) v += vrep[(r * BATCH + b) * NSEG + tid];
    s_vs[tid] = v;
  }
  if (tid == 0) s_dl = 0.f;
  __syncthreads();
  for (int i = tid; i < NLBL * DIM; i += 256) {
    const int l = i >> 5, d = i & 31;
    s_m[l * 33 + d] = cb[NSEG + d * NSEG + (l + 1)] / fmaxf(s_cnt[l + 1], 1.f);
  }
  if (tid < NLBL) s_p[tid] = (s_cnt[tid + 1] > 0.f) ? 1 : 0;
  __syncthreads();
  float dl = 0.f;
  for (int p = tid; p < NLBL * NLBL; p += 256) {
    const int i = p / NLBL, j = p - (p / NLBL) * NLBL;
    if (i != j && s_p[i] && s_p[j]) {
      float sq = 0.f;
      #pragma unroll
      for (int d = 0; d < DIM; ++d) {
        const float t = s_m[i * 33 + d] - s_m[j * 33 + d];
        sq += t * t;
      }
      const float r = DD - sqrtf(sq);
      if (r > 0.f) dl += r * r;
    }
  }
  atomicAdd(&s_dl, dl);
  __syncthreads();
  if (tid == 0) {
    float nl = 0.f, var = 0.f;
    for (int l = 1; l <= NLBL; ++l)
      if (s_cnt[l] > 0.f) { nl += 1.f; var += s_vs[l] / s_cnt[l]; }
    const float vb = (nl > 0.f) ? var / nl : 0.f;
    const float db = (nl > 1.f) ? s_dl / fmaxf(nl * (nl - 1.f), 1.f) * 0.5f : 0.f;
    atomicAdd(&out[0], vb / (float)BATCH);
    atomicAdd(&out[1], db / (float)BATCH);
  }
}

extern "C" void kernel_launch(void* const* d_in, const int* in_sizes, int n_in,
                              void* d_out, int out_size, void* d_ws, size_t ws_size,
                              hipStream_t stream) {
  const float* emb = (const float*)d_in[0];
  const int*   seg = (const int*)d_in[1];
  float* out = (float*)d_out;
  float* ws  = (float*)d_ws;
  const int N = in_sizes[1] / BATCH;              // 65536

  float* canon = ws;                              // 8*693
  float* vrep  = canon + BATCH * SEGF;            // 16*8*21
  float* probe = vrep + VREP * BATCH * NSEG;      // 32768 floats

  hipMemsetAsync(canon, 0,
                 (size_t)(BATCH * SEGF + VREP * BATCH * NSEG) * sizeof(float), stream);
  hipMemsetAsync(d_out, 0, (size_t)out_size * sizeof(float), stream);

  k_cnt  <<<dim3(N / 4096, BATCH), 256, 0, stream>>>(seg, canon, N);
  k_sums2<<<dim3(N / 16384, DIM, BATCH), 256, 0, stream>>>(emb, seg, canon, N);
  k_var  <<<dim3(N / 256, BATCH), 256, 0, stream>>>(emb, seg, canon, vrep, N);
  k_final<<<dim3(BATCH), 256, 0, stream>>>(canon, vrep, out);

  // diagnostics (ws-only writes)
  p_load<<<dim3(N / 1024, BATCH, 4), 256, 0, stream>>>(emb, seg, probe, N);
  p_ds  <<<dim3(64, 8, 4), 256, 0, stream>>>(probe);
}

// Round 6
// 63.309 us; speedup vs baseline: 2.8471x; 2.3293x over previous
//
#include <hip/hip_runtime.h>

#define NSEG 21
#define NLBL 20
#define DIM  32
#define VREP 16
#define NREP 16
#define DV   0.5f
#define DD   3.0f
#define BATCH 8
#define SEGF 693     // per-batch canonical: [21 counts][672 sums d-major: 21 + d*21 + s]

// k_moments: segment sums (+counts when d==0) with ZERO LDS atomics and zero
// LDS-RMW. One-hot register accumulation over labels 1..20 (label 0 is never
// used by the loss), shfl_xor butterfly, 20 global atomics per block.
__global__ __launch_bounds__(256)
void k_moments(const float* __restrict__ emb, const int* __restrict__ seg,
               float* __restrict__ canon, int N) {
  __shared__ float red[8 * NLBL];            // [4 waves][20] sums, then counts
  const int tid = threadIdx.x;
  const int sp = blockIdx.x, d = blockIdx.y, b = blockIdx.z;
  const int n0 = sp * 16384;
  const float4* e4 = (const float4*)(emb + ((size_t)b * DIM + d) * N + n0) + tid;
  const int4*   g4 = (const int4*)(seg + (size_t)b * N + n0) + tid;

  float acc[NLBL], cnt[NLBL];
  #pragma unroll
  for (int l = 0; l < NLBL; ++l) { acc[l] = 0.f; cnt[l] = 0.f; }

  if (d == 0) {
    for (int u = 0; u < 16; u += 4) {
      float4 e[4]; int4 s[4];
      #pragma unroll
      for (int k = 0; k < 4; ++k) { e[k] = e4[(u + k) * 256]; s[k] = g4[(u + k) * 256]; }
      #pragma unroll
      for (int k = 0; k < 4; ++k) {
        #pragma unroll
        for (int l = 0; l < NLBL; ++l) {
          const int lab = l + 1;
          if (s[k].x == lab) { acc[l] += e[k].x; cnt[l] += 1.f; }
          if (s[k].y == lab) { acc[l] += e[k].y; cnt[l] += 1.f; }
          if (s[k].z == lab) { acc[l] += e[k].z; cnt[l] += 1.f; }
          if (s[k].w == lab) { acc[l] += e[k].w; cnt[l] += 1.f; }
        }
      }
    }
  } else {
    for (int u = 0; u < 16; u += 4) {
      float4 e[4]; int4 s[4];
      #pragma unroll
      for (int k = 0; k < 4; ++k) { e[k] = e4[(u + k) * 256]; s[k] = g4[(u + k) * 256]; }
      #pragma unroll
      for (int k = 0; k < 4; ++k) {
        #pragma unroll
        for (int l = 0; l < NLBL; ++l) {
          const int lab = l + 1;
          if (s[k].x == lab) acc[l] += e[k].x;
          if (s[k].y == lab) acc[l] += e[k].y;
          if (s[k].z == lab) acc[l] += e[k].z;
          if (s[k].w == lab) acc[l] += e[k].w;
        }
      }
    }
  }

  const int wave = tid >> 6, lane = tid & 63;
  #pragma unroll
  for (int l = 0; l < NLBL; ++l) {
    float a = acc[l];
    #pragma unroll
    for (int off = 32; off; off >>= 1) a += __shfl_xor(a, off, 64);
    acc[l] = a;
  }
  if (lane == 0) {
    #pragma unroll
    for (int l = 0; l < NLBL; ++l) red[wave * NLBL + l] = acc[l];
  }
  if (d == 0) {
    #pragma unroll
    for (int l = 0; l < NLBL; ++l) {
      float c = cnt[l];
      #pragma unroll
      for (int off = 32; off; off >>= 1) c += __shfl_xor(c, off, 64);
      cnt[l] = c;
    }
    if (lane == 0) {
      #pragma unroll
      for (int l = 0; l < NLBL; ++l) red[(4 + wave) * NLBL + l] = cnt[l];
    }
  }
  __syncthreads();
  if (tid < NLBL) {
    const float v = red[tid] + red[NLBL + tid] + red[2 * NLBL + tid] + red[3 * NLBL + tid];
    atomicAdd(&canon[b * SEGF + NSEG + d * NSEG + (tid + 1)], v);
    if (d == 0) {
      const float c = red[4 * NLBL + tid] + red[5 * NLBL + tid] +
                      red[6 * NLBL + tid] + red[7 * NLBL + tid];
      atomicAdd(&canon[b * SEGF + (tid + 1)], c);
    }
  }
}

__global__ __launch_bounds__(256)
void k_var(const float* __restrict__ emb, const int* __restrict__ seg,
           const float* __restrict__ canon, float* __restrict__ vrep, int N) {
  __shared__ float s_m[NSEG * 33];
  __shared__ float s_c[NSEG];
  __shared__ float s_v[NREP * NSEG];
  const int tid = threadIdx.x;
  const int bx = blockIdx.x, b = blockIdx.y;
  const float* cb = canon + b * SEGF;
  if (tid < NSEG) s_c[tid] = fmaxf(cb[tid], 1.f);
  for (int i = tid; i < NREP * NSEG; i += 256) s_v[i] = 0.f;
  __syncthreads();
  for (int i = tid; i < DIM * NSEG; i += 256) {
    const int d = i / NSEG, s = i - d * NSEG;
    s_m[s * 33 + d] = cb[NSEG + i] / s_c[s];
  }
  __syncthreads();
  const int n = bx * 256 + tid;
  const int sl = seg[(size_t)b * N + n];
  const size_t base = (size_t)b * DIM * N + n;
  const int ml = sl * 33;
  float q = 0.f;
  #pragma unroll
  for (int d = 0; d < DIM; ++d) {
    const float e = emb[base + (size_t)d * N];
    const float t = e - s_m[ml + d];
    q += t * t;
  }
  if (sl > 0) {
    const float r = sqrtf(q) - DV;
    if (r > 0.f) atomicAdd(&s_v[(tid & (NREP - 1)) * NSEG + sl], r * r);
  }
  __syncthreads();
  if (tid < NSEG) {
    float v = 0.f;
    #pragma unroll
    for (int r = 0; r < NREP; ++r) v += s_v[r * NSEG + tid];
    atomicAdd(&vrep[((bx & (VREP - 1)) * BATCH + b) * NSEG + tid], v);
  }
}

__global__ __launch_bounds__(256)
void k_final(const float* __restrict__ canon, const float* __restrict__ vrep,
             float* __restrict__ out) {
  __shared__ float s_m[NLBL * 33];
  __shared__ float s_cnt[NSEG];
  __shared__ float s_vs[NSEG];
  __shared__ int   s_p[NLBL];
  __shared__ float s_dl;
  const int b = blockIdx.x;
  const int tid = threadIdx.x;
  const float* cb = canon + b * SEGF;
  if (tid < NSEG) {
    s_cnt[tid] = cb[tid];
    float v = 0.f;
    for (int r = 0; r < VREP; ++r) v += vrep[(r * BATCH + b) * NSEG + tid];
    s_vs[tid] = v;
  }
  if (tid == 0) s_dl = 0.f;
  __syncthreads();
  for (int i = tid; i < NLBL * DIM; i += 256) {
    const int l = i >> 5, d = i & 31;
    s_m[l * 33 + d] = cb[NSEG + d * NSEG + (l + 1)] / fmaxf(s_cnt[l + 1], 1.f);
  }
  if (tid < NLBL) s_p[tid] = (s_cnt[tid + 1] > 0.f) ? 1 : 0;
  __syncthreads();
  float dl = 0.f;
  for (int p = tid; p < NLBL * NLBL; p += 256) {
    const int i = p / NLBL, j = p - (p / NLBL) * NLBL;
    if (i != j && s_p[i] && s_p[j]) {
      float sq = 0.f;
      #pragma unroll
      for (int d = 0; d < DIM; ++d) {
        const float t = s_m[i * 33 + d] - s_m[j * 33 + d];
        sq += t * t;
      }
      const float r = DD - sqrtf(sq);
      if (r > 0.f) dl += r * r;
    }
  }
  atomicAdd(&s_dl, dl);
  __syncthreads();
  if (tid == 0) {
    float nl = 0.f, var = 0.f;
    for (int l = 1; l <= NLBL; ++l)
      if (s_cnt[l] > 0.f) { nl += 1.f; var += s_vs[l] / s_cnt[l]; }
    const float vb = (nl > 0.f) ? var / nl : 0.f;
    const float db = (nl > 1.f) ? s_dl / fmaxf(nl * (nl - 1.f), 1.f) * 0.5f : 0.f;
    atomicAdd(&out[0], vb / (float)BATCH);
    atomicAdd(&out[1], db / (float)BATCH);
  }
}

extern "C" void kernel_launch(void* const* d_in, const int* in_sizes, int n_in,
                              void* d_out, int out_size, void* d_ws, size_t ws_size,
                              hipStream_t stream) {
  const float* emb = (const float*)d_in[0];
  const int*   seg = (const int*)d_in[1];
  float* out = (float*)d_out;
  float* ws  = (float*)d_ws;
  const int N = in_sizes[1] / BATCH;              // 65536

  float* canon = ws;                              // 8*693
  float* vrep  = canon + BATCH * SEGF;            // 16*8*21

  hipMemsetAsync(canon, 0,
                 (size_t)(BATCH * SEGF + VREP * BATCH * NSEG) * sizeof(float), stream);
  hipMemsetAsync(d_out, 0, (size_t)out_size * sizeof(float), stream);

  k_moments<<<dim3(N / 16384, DIM, BATCH), 256, 0, stream>>>(emb, seg, canon, N);
  k_var    <<<dim3(N / 256, BATCH), 256, 0, stream>>>(emb, seg, canon, vrep, N);
  k_final  <<<dim3(BATCH), 256, 0, stream>>>(canon, vrep, out);
}